// Round 1
// baseline (1178.536 us; speedup 1.0000x reference)
//
#include <hip/hip_runtime.h>
#include <hip/hip_bf16.h>
#include <math.h>

#define NN 100000
#define NE 1000000
#define DD 64
#define NG 128
#define NL 3

// ---------------- CSR build ----------------

__global__ void zero_k(int* a, int n) {
    int i = blockIdx.x * blockDim.x + threadIdx.x;
    if (i < n) a[i] = 0;
}

__global__ void hist_k(const int* __restrict__ dst, int* __restrict__ deg) {
    int e = blockIdx.x * blockDim.x + threadIdx.x;
    if (e < NE) atomicAdd(&deg[dst[e]], 1);
}

__global__ void scan1_k(const int* __restrict__ deg, int* __restrict__ bsum) {
    int i = blockIdx.x * 256 + threadIdx.x;
    int v = (i < NN) ? deg[i] : 0;
#pragma unroll
    for (int off = 32; off; off >>= 1) v += __shfl_xor(v, off);
    __shared__ int s[4];
    if ((threadIdx.x & 63) == 0) s[threadIdx.x >> 6] = v;
    __syncthreads();
    if (threadIdx.x == 0) bsum[blockIdx.x] = s[0] + s[1] + s[2] + s[3];
}

__global__ void scan2_k(int* bsum, int* rowstart, int nb) {
    // single thread serial scan over block sums (nb ~ 391)
    int run = 0;
    for (int b = 0; b < nb; b++) { int t = bsum[b]; bsum[b] = run; run += t; }
    rowstart[NN] = run;
}

__global__ void scan3_k(const int* __restrict__ deg, const int* __restrict__ bsum,
                        int* __restrict__ rowstart) {
    __shared__ int tmp[256];
    int t = threadIdx.x;
    int i = blockIdx.x * 256 + t;
    int v = (i < NN) ? deg[i] : 0;
    tmp[t] = v;
    __syncthreads();
#pragma unroll
    for (int off = 1; off < 256; off <<= 1) {
        int add = (t >= off) ? tmp[t - off] : 0;
        __syncthreads();
        tmp[t] += add;
        __syncthreads();
    }
    if (i < NN) rowstart[i] = tmp[t] - v + bsum[blockIdx.x];
}

__global__ void scatter_k(const int* __restrict__ src, const int* __restrict__ dst,
                          const int* __restrict__ rowstart, int* __restrict__ cursor,
                          int* __restrict__ csr_src) {
    int e = blockIdx.x * blockDim.x + threadIdx.x;
    if (e < NE) {
        int d = dst[e];
        int pos = atomicAdd(&cursor[d], 1);
        csr_src[rowstart[d] + pos] = src[e];
    }
}

// ---------------- GEMM: out[N,64] = h[N,64] @ W[64,64] + b ----------------

__global__ __launch_bounds__(256) void gemm_k(const float* __restrict__ hin,
                                              const float* __restrict__ W,
                                              const float* __restrict__ bias,
                                              float* __restrict__ outp) {
    __shared__ float sh[64][68];  // padded to break bank conflicts on column reads
    __shared__ float sw[64][64];
    int t = threadIdx.x;
    int rowbase = blockIdx.x * 64;

#pragma unroll
    for (int c4 = 0; c4 < 4; c4++) {
        int lin = c4 * 256 + t;       // 0..1023
        int r = lin >> 4;             // 0..63
        int c = (lin & 15) << 2;      // 0..60 step 4
        int grow = rowbase + r;
        float4 hv = make_float4(0.f, 0.f, 0.f, 0.f);
        if (grow < NN) hv = *(const float4*)&hin[(size_t)grow * DD + c];
        *(float4*)&sh[r][c] = hv;
        float4 wv = *(const float4*)&W[r * DD + c];
        *(float4*)&sw[r][c] = wv;
    }
    __syncthreads();

    int tc = t & 15, tr = t >> 4;     // tc 0..15, tr 0..15
    int c0 = tc * 4, r0 = tr * 4;
    float acc[4][4];
    float4 bvec = *(const float4*)&bias[c0];
#pragma unroll
    for (int i = 0; i < 4; i++) {
        acc[i][0] = bvec.x; acc[i][1] = bvec.y; acc[i][2] = bvec.z; acc[i][3] = bvec.w;
    }

#pragma unroll 8
    for (int kk = 0; kk < 64; kk++) {
        float4 b4 = *(const float4*)&sw[kk][c0];
        float a0 = sh[r0 + 0][kk];
        float a1 = sh[r0 + 1][kk];
        float a2 = sh[r0 + 2][kk];
        float a3 = sh[r0 + 3][kk];
        acc[0][0] += a0 * b4.x; acc[0][1] += a0 * b4.y; acc[0][2] += a0 * b4.z; acc[0][3] += a0 * b4.w;
        acc[1][0] += a1 * b4.x; acc[1][1] += a1 * b4.y; acc[1][2] += a1 * b4.z; acc[1][3] += a1 * b4.w;
        acc[2][0] += a2 * b4.x; acc[2][1] += a2 * b4.y; acc[2][2] += a2 * b4.z; acc[2][3] += a2 * b4.w;
        acc[3][0] += a3 * b4.x; acc[3][1] += a3 * b4.y; acc[3][2] += a3 * b4.z; acc[3][3] += a3 * b4.w;
    }

#pragma unroll
    for (int i = 0; i < 4; i++) {
        int grow = rowbase + r0 + i;
        if (grow < NN) {
            float4 o = make_float4(acc[i][0], acc[i][1], acc[i][2], acc[i][3]);
            *(float4*)&outp[(size_t)grow * DD + c0] = o;
        }
    }
}

// ---------------- per-node attention aggregate + skip + relu ----------------

__global__ __launch_bounds__(256) void agg_k(const float* __restrict__ qb,
                                             const float* __restrict__ kb,
                                             const float* __restrict__ vb,
                                             const float* __restrict__ skb,
                                             const int* __restrict__ rowstart,
                                             const int* __restrict__ csr_src,
                                             float* __restrict__ hout) {
    __shared__ float wsc[4][64];
    int nid = (blockIdx.x * blockDim.x + threadIdx.x) >> 6;  // one wave per node
    int lane = threadIdx.x & 63;
    int wv = threadIdx.x >> 6;
    if (nid >= NN) return;
    int r0 = rowstart[nid], r1 = rowstart[nid + 1];
    float qv = qb[(size_t)nid * DD + lane];

    // pass 1: scores + running max (score is wave-uniform after reduce)
    float m = -3.0e38f;
    for (int j = r0; j < r1; j++) {
        int s = csr_src[j];
        float tt = qv * kb[(size_t)s * DD + lane];
#pragma unroll
        for (int off = 32; off; off >>= 1) tt += __shfl_xor(tt, off);
        tt *= 0.125f;  // 1/sqrt(64)
        int idx = j - r0;
        if (idx < 64) wsc[wv][idx] = tt;   // uniform addr, uniform value
        m = fmaxf(m, tt);
    }

    // pass 2: expsum + weighted aggregate
    float se = 0.f, acc = 0.f;
    for (int j = r0; j < r1; j++) {
        int s = csr_src[j];
        int idx = j - r0;
        float sco;
        if (idx < 64) {
            sco = wsc[wv][idx];
        } else {  // overflow fallback: recompute dot (degree > 64, ~never)
            float tt = qv * kb[(size_t)s * DD + lane];
#pragma unroll
            for (int off = 32; off; off >>= 1) tt += __shfl_xor(tt, off);
            sco = tt * 0.125f;
        }
        float w = __expf(sco - m);
        se += w;
        acc += w * vb[(size_t)s * DD + lane];
    }

    float r = acc / (se + 1e-16f) + skb[(size_t)nid * DD + lane];
    hout[(size_t)nid * DD + lane] = fmaxf(r, 0.f);
}

// ---------------- global add pool (batch is sorted) ----------------

__device__ __forceinline__ int lbound(const int* __restrict__ a, int n, int key) {
    int lo = 0, hi = n;
    while (lo < hi) {
        int mid = (lo + hi) >> 1;
        if (a[mid] < key) lo = mid + 1; else hi = mid;
    }
    return lo;
}

__global__ __launch_bounds__(256) void pool_k(const float* __restrict__ h,
                                              const int* __restrict__ batch,
                                              float* __restrict__ pooled) {
    int g = blockIdx.x;
    int lo = lbound(batch, NN, g);
    int hi = lbound(batch, NN, g + 1);
    int lane = threadIdx.x & 63;
    int wv = threadIdx.x >> 6;
    float s = 0.f;
    for (int i = lo + wv; i < hi; i += 4) s += h[(size_t)i * DD + lane];
    __shared__ float red[4][64];
    red[wv][lane] = s;
    __syncthreads();
    if (wv == 0) pooled[g * DD + lane] = red[0][lane] + red[1][lane] + red[2][lane] + red[3][lane];
}

// ---------------- head: relu(pooled2 @ W1 + b1) @ W2 + b2 ----------------

__global__ __launch_bounds__(64) void head_k(const float* __restrict__ pooled2,
                                             const float* __restrict__ W1,
                                             const float* __restrict__ b1,
                                             const float* __restrict__ W2,
                                             const float* __restrict__ b2,
                                             float* __restrict__ out) {
    int g = blockIdx.x;
    int c = threadIdx.x;  // 0..63
    __shared__ float pg[64], p[64];
    pg[c] = pooled2[g * DD + c];
    __syncthreads();
    float a = b1[c];
#pragma unroll 8
    for (int kk = 0; kk < 64; kk++) a += pg[kk] * W1[kk * DD + c];
    p[c] = fmaxf(a, 0.f);
    __syncthreads();
    if (c < 10) {
        float o = b2[c];
#pragma unroll 8
        for (int kk = 0; kk < 64; kk++) o += p[kk] * W2[kk * 10 + c];
        out[g * 10 + c] = o;
    }
}

// ---------------- launch ----------------

extern "C" void kernel_launch(void* const* d_in, const int* in_sizes, int n_in,
                              void* d_out, int out_size, void* d_ws, size_t ws_size,
                              hipStream_t stream) {
    const float* x    = (const float*)d_in[0];
    const int*   ei   = (const int*)d_in[1];
    const int*   batch= (const int*)d_in[2];
    const float* Wq   = (const float*)d_in[3];
    const float* bq   = (const float*)d_in[4];
    const float* Wk   = (const float*)d_in[5];
    const float* bk   = (const float*)d_in[6];
    const float* Wv   = (const float*)d_in[7];
    const float* bv   = (const float*)d_in[8];
    const float* Wsp  = (const float*)d_in[9];
    const float* bsp  = (const float*)d_in[10];
    const float* W1   = (const float*)d_in[11];
    const float* b1   = (const float*)d_in[12];
    const float* W2   = (const float*)d_in[13];
    const float* b2   = (const float*)d_in[14];
    float* out = (float*)d_out;
    float* pooled = out + NG * 10;  // [3][128][64] region of d_out

    const int* srcv = ei;
    const int* dstv = ei + NE;

    float* h   = (float*)d_ws;
    float* qb  = h   + (size_t)NN * DD;
    float* kb  = qb  + (size_t)NN * DD;
    float* vb  = kb  + (size_t)NN * DD;
    float* skb = vb  + (size_t)NN * DD;
    int* rowstart = (int*)(skb + (size_t)NN * DD);
    int* deg      = rowstart + (NN + 1);
    int* cursor   = deg + NN;          // deg & cursor contiguous -> one zero pass
    int* csr_src  = cursor + NN;
    int* bsum     = csr_src + NE;      // ~391 entries

    int nbN = (NN + 255) / 256;

    zero_k<<<(2 * NN + 255) / 256, 256, 0, stream>>>(deg, 2 * NN);
    hist_k<<<(NE + 255) / 256, 256, 0, stream>>>(dstv, deg);
    scan1_k<<<nbN, 256, 0, stream>>>(deg, bsum);
    scan2_k<<<1, 1, 0, stream>>>(bsum, rowstart, nbN);
    scan3_k<<<nbN, 256, 0, stream>>>(deg, bsum, rowstart);
    scatter_k<<<(NE + 255) / 256, 256, 0, stream>>>(srcv, dstv, rowstart, cursor, csr_src);

    int gtiles = (NN + 63) / 64;
    for (int l = 0; l < NL; l++) {
        const float* hin = (l == 0) ? x : h;
        gemm_k<<<gtiles, 256, 0, stream>>>(hin, Wq  + l * DD * DD, bq  + l * DD, qb);
        gemm_k<<<gtiles, 256, 0, stream>>>(hin, Wk  + l * DD * DD, bk  + l * DD, kb);
        gemm_k<<<gtiles, 256, 0, stream>>>(hin, Wv  + l * DD * DD, bv  + l * DD, vb);
        gemm_k<<<gtiles, 256, 0, stream>>>(hin, Wsp + l * DD * DD, bsp + l * DD, skb);
        agg_k<<<(NN * 64) / 256, 256, 0, stream>>>(qb, kb, vb, skb, rowstart, csr_src, h);
        pool_k<<<NG, 256, 0, stream>>>(h, batch, pooled + l * NG * DD);
    }
    head_k<<<NG, 64, 0, stream>>>(pooled + 2 * NG * DD, W1, b1, W2, b2, out);
}

// Round 2
// 718.209 us; speedup vs baseline: 1.6409x; 1.6409x over previous
//
#include <hip/hip_runtime.h>
#include <hip/hip_bf16.h>
#include <math.h>

#define NN 100000
#define NE 1000000
#define DD 64
#define NG 128
#define NL 3

typedef unsigned short ushort_t;
typedef __attribute__((ext_vector_type(8))) short short8v;
typedef __attribute__((ext_vector_type(4))) float f32x4;

__device__ __forceinline__ ushort_t f2bf(float f) {
    __hip_bfloat16 h = __float2bfloat16(f);
    return *reinterpret_cast<ushort_t*>(&h);
}
__device__ __forceinline__ float bf2f(ushort_t u) {
    unsigned v = ((unsigned)u) << 16;
    return __builtin_bit_cast(float, v);
}

// ---------------- CSR build ----------------

__global__ void zero_k(int* a, int n) {
    int i = blockIdx.x * blockDim.x + threadIdx.x;
    if (i < n) a[i] = 0;
}

__global__ void hist_k(const int* __restrict__ dst, int* __restrict__ deg) {
    int e = blockIdx.x * blockDim.x + threadIdx.x;
    if (e < NE) atomicAdd(&deg[dst[e]], 1);
}

__global__ void scan1_k(const int* __restrict__ deg, int* __restrict__ bsum) {
    int i = blockIdx.x * 256 + threadIdx.x;
    int v = (i < NN) ? deg[i] : 0;
#pragma unroll
    for (int off = 32; off; off >>= 1) v += __shfl_xor(v, off);
    __shared__ int s[4];
    if ((threadIdx.x & 63) == 0) s[threadIdx.x >> 6] = v;
    __syncthreads();
    if (threadIdx.x == 0) bsum[blockIdx.x] = s[0] + s[1] + s[2] + s[3];
}

__global__ void scan2_k(int* bsum, int* rowstart, int nb) {
    int run = 0;
    for (int b = 0; b < nb; b++) { int t = bsum[b]; bsum[b] = run; run += t; }
    rowstart[NN] = run;
}

__global__ void scan3_k(const int* __restrict__ deg, const int* __restrict__ bsum,
                        int* __restrict__ rowstart) {
    __shared__ int tmp[256];
    int t = threadIdx.x;
    int i = blockIdx.x * 256 + t;
    int v = (i < NN) ? deg[i] : 0;
    tmp[t] = v;
    __syncthreads();
#pragma unroll
    for (int off = 1; off < 256; off <<= 1) {
        int add = (t >= off) ? tmp[t - off] : 0;
        __syncthreads();
        tmp[t] += add;
        __syncthreads();
    }
    if (i < NN) rowstart[i] = tmp[t] - v + bsum[blockIdx.x];
}

__global__ void scatter_k(const int* __restrict__ src, const int* __restrict__ dst,
                          const int* __restrict__ rowstart, int* __restrict__ cursor,
                          int* __restrict__ csr_src) {
    int e = blockIdx.x * blockDim.x + threadIdx.x;
    if (e < NE) {
        int d = dst[e];
        int pos = atomicAdd(&cursor[d], 1);
        csr_src[rowstart[d] + pos] = src[e];
    }
}

// ---------------- f32 -> bf16 convert ----------------

__global__ void cvt_k(const float* __restrict__ x, ushort_t* __restrict__ o, int n) {
    int i = blockIdx.x * blockDim.x + threadIdx.x;
    int base = i * 4;
    if (base + 3 < n) {
        float4 v = *(const float4*)&x[base];
        o[base + 0] = f2bf(v.x); o[base + 1] = f2bf(v.y);
        o[base + 2] = f2bf(v.z); o[base + 3] = f2bf(v.w);
    } else {
        for (int k = base; k < n; k++) o[k] = f2bf(x[k]);
    }
}

// ---------------- fused 4-matrix MFMA GEMM ----------------
// out_m[N,64](bf16) = hbf[N,64] @ W_m[64,64] + b_m  for m in {q,k,v,skip}
// block = 256 thr = 4 waves; wave w handles matrix w over 64 rows.

__global__ __launch_bounds__(256) void gemm4_k(const ushort_t* __restrict__ hbf,
                                               const float* __restrict__ Wq, const float* __restrict__ bq_,
                                               const float* __restrict__ Wk, const float* __restrict__ bk_,
                                               const float* __restrict__ Wv, const float* __restrict__ bv_,
                                               const float* __restrict__ Ws_, const float* __restrict__ bs_,
                                               ushort_t* __restrict__ qo, ushort_t* __restrict__ ko,
                                               ushort_t* __restrict__ vo, ushort_t* __restrict__ so) {
    __shared__ ushort_t sa[64][72];  // 144B rows: 16B-aligned chunks, 2-way-max bank alias
    int t = threadIdx.x;
    int rowbase = blockIdx.x * 64;
    int lane = t & 63;
    int wv = t >> 6;
    int ln = lane & 15;   // A row within tile / output col within ct
    int lq = lane >> 4;   // k-chunk selector

    // stage A tile (64 rows x 64 bf16)
#pragma unroll
    for (int it = 0; it < 2; ++it) {
        int lin = it * 256 + t;       // 0..511
        int r = lin >> 3;             // 0..63
        int c8 = (lin & 7) * 8;       // 0..56
        int grow = rowbase + r;
        short8v val = (short8v)0;
        if (grow < NN) val = *(const short8v*)&hbf[(size_t)grow * DD + c8];
        *(short8v*)&sa[r][c8] = val;
    }

    const float* Wsel = (wv == 0) ? Wq : (wv == 1) ? Wk : (wv == 2) ? Wv : Ws_;
    const float* bsel = (wv == 0) ? bq_ : (wv == 1) ? bk_ : (wv == 2) ? bv_ : bs_;
    ushort_t* osel    = (wv == 0) ? qo : (wv == 1) ? ko : (wv == 2) ? vo : so;

    // B fragments: lane holds B[k][n] with n = ct*16+ln, k = ks*32 + lq*8 + j
    short8v bfrag[4][2];
#pragma unroll
    for (int ct = 0; ct < 4; ct++) {
#pragma unroll
        for (int ks = 0; ks < 2; ks++) {
            short8v f;
#pragma unroll
            for (int j = 0; j < 8; j++) {
                f[j] = (short)f2bf(Wsel[(ks * 32 + lq * 8 + j) * DD + ct * 16 + ln]);
            }
            bfrag[ct][ks] = f;
        }
    }
    float bias[4];
#pragma unroll
    for (int ct = 0; ct < 4; ct++) bias[ct] = bsel[ct * 16 + ln];

    __syncthreads();

#pragma unroll
    for (int rt = 0; rt < 4; rt++) {
        // A frags: lane: row rt*16+ln, k-cols lq*8 (+32 for ks=1)
        short8v a0 = *(const short8v*)&sa[rt * 16 + ln][lq * 8];
        short8v a1 = *(const short8v*)&sa[rt * 16 + ln][32 + lq * 8];
#pragma unroll
        for (int ct = 0; ct < 4; ct++) {
            f32x4 acc;
            acc[0] = bias[ct]; acc[1] = bias[ct]; acc[2] = bias[ct]; acc[3] = bias[ct];
            acc = __builtin_amdgcn_mfma_f32_16x16x32_bf16(a0, bfrag[ct][0], acc, 0, 0, 0);
            acc = __builtin_amdgcn_mfma_f32_16x16x32_bf16(a1, bfrag[ct][1], acc, 0, 0, 0);
            // D: col = lane&15 (= ct*16+ln), row = lq*4 + i
#pragma unroll
            for (int i = 0; i < 4; i++) {
                int grow = rowbase + rt * 16 + lq * 4 + i;
                if (grow < NN) osel[(size_t)grow * DD + ct * 16 + ln] = f2bf(acc[i]);
            }
        }
    }
}

// ---------------- per-node attention aggregate + skip + relu (bf16, 4-way ILP) ----------------

__global__ __launch_bounds__(256) void agg_k(const ushort_t* __restrict__ qb,
                                             const ushort_t* __restrict__ kb,
                                             const ushort_t* __restrict__ vb,
                                             const ushort_t* __restrict__ skb,
                                             const int* __restrict__ rowstart,
                                             const int* __restrict__ csr_src,
                                             ushort_t* __restrict__ hout) {
    __shared__ float wsc[4][64];
    int nid = (blockIdx.x * blockDim.x + threadIdx.x) >> 6;
    int lane = threadIdx.x & 63;
    int wv = threadIdx.x >> 6;
    if (nid >= NN) return;
    int r0 = rowstart[nid], r1 = rowstart[nid + 1];
    float qv = bf2f(qb[(size_t)nid * DD + lane]);

    // pass 1: scores (4-deep batches)
    float m = -3.0e38f;
    int j = r0;
    for (; j + 4 <= r1; j += 4) {
        int s0 = csr_src[j + 0], s1 = csr_src[j + 1], s2 = csr_src[j + 2], s3 = csr_src[j + 3];
        float t0 = qv * bf2f(kb[(size_t)s0 * DD + lane]);
        float t1 = qv * bf2f(kb[(size_t)s1 * DD + lane]);
        float t2 = qv * bf2f(kb[(size_t)s2 * DD + lane]);
        float t3 = qv * bf2f(kb[(size_t)s3 * DD + lane]);
#pragma unroll
        for (int off = 32; off; off >>= 1) {
            t0 += __shfl_xor(t0, off);
            t1 += __shfl_xor(t1, off);
            t2 += __shfl_xor(t2, off);
            t3 += __shfl_xor(t3, off);
        }
        t0 *= 0.125f; t1 *= 0.125f; t2 *= 0.125f; t3 *= 0.125f;
        int idx = j - r0;
        if (lane == 0) {
            if (idx + 0 < 64) wsc[wv][idx + 0] = t0;
            if (idx + 1 < 64) wsc[wv][idx + 1] = t1;
            if (idx + 2 < 64) wsc[wv][idx + 2] = t2;
            if (idx + 3 < 64) wsc[wv][idx + 3] = t3;
        }
        m = fmaxf(m, fmaxf(fmaxf(t0, t1), fmaxf(t2, t3)));
    }
    for (; j < r1; j++) {
        int s = csr_src[j];
        float tt = qv * bf2f(kb[(size_t)s * DD + lane]);
#pragma unroll
        for (int off = 32; off; off >>= 1) tt += __shfl_xor(tt, off);
        tt *= 0.125f;
        int idx = j - r0;
        if (lane == 0 && idx < 64) wsc[wv][idx] = tt;
        m = fmaxf(m, tt);
    }

    // pass 2: expsum + weighted aggregate (4-deep batches over cached scores)
    float se = 0.f, acc = 0.f;
    int deg = r1 - r0;
    int fastN = (deg < 64 ? deg : 64) & ~3;
    int jf = r0 + fastN;
    j = r0;
    for (; j < jf; j += 4) {
        int s0 = csr_src[j + 0], s1 = csr_src[j + 1], s2 = csr_src[j + 2], s3 = csr_src[j + 3];
        int idx = j - r0;
        float w0 = __expf(wsc[wv][idx + 0] - m);
        float w1 = __expf(wsc[wv][idx + 1] - m);
        float w2 = __expf(wsc[wv][idx + 2] - m);
        float w3 = __expf(wsc[wv][idx + 3] - m);
        float v0 = bf2f(vb[(size_t)s0 * DD + lane]);
        float v1 = bf2f(vb[(size_t)s1 * DD + lane]);
        float v2 = bf2f(vb[(size_t)s2 * DD + lane]);
        float v3 = bf2f(vb[(size_t)s3 * DD + lane]);
        se += (w0 + w1) + (w2 + w3);
        acc += w0 * v0 + w1 * v1 + w2 * v2 + w3 * v3;
    }
    for (; j < r1; j++) {
        int s = csr_src[j];
        int idx = j - r0;
        float sco;
        if (idx < 64) {
            sco = wsc[wv][idx];
        } else {
            float tt = qv * bf2f(kb[(size_t)s * DD + lane]);
#pragma unroll
            for (int off = 32; off; off >>= 1) tt += __shfl_xor(tt, off);
            sco = tt * 0.125f;
        }
        float w = __expf(sco - m);
        se += w;
        acc += w * bf2f(vb[(size_t)s * DD + lane]);
    }

    float r = acc / (se + 1e-16f) + bf2f(skb[(size_t)nid * DD + lane]);
    hout[(size_t)nid * DD + lane] = f2bf(fmaxf(r, 0.f));
}

// ---------------- global add pool (batch is sorted) ----------------

__device__ __forceinline__ int lbound(const int* __restrict__ a, int n, int key) {
    int lo = 0, hi = n;
    while (lo < hi) {
        int mid = (lo + hi) >> 1;
        if (a[mid] < key) lo = mid + 1; else hi = mid;
    }
    return lo;
}

__global__ __launch_bounds__(256) void pool_k(const ushort_t* __restrict__ h,
                                              const int* __restrict__ batch,
                                              float* __restrict__ pooled) {
    int g = blockIdx.x;
    int lo = lbound(batch, NN, g);
    int hi = lbound(batch, NN, g + 1);
    int lane = threadIdx.x & 63;
    int wv = threadIdx.x >> 6;
    float s = 0.f;
    for (int i = lo + wv; i < hi; i += 4) s += bf2f(h[(size_t)i * DD + lane]);
    __shared__ float red[4][64];
    red[wv][lane] = s;
    __syncthreads();
    if (wv == 0) pooled[g * DD + lane] = red[0][lane] + red[1][lane] + red[2][lane] + red[3][lane];
}

// ---------------- head ----------------

__global__ __launch_bounds__(64) void head_k(const float* __restrict__ pooled2,
                                             const float* __restrict__ W1,
                                             const float* __restrict__ b1,
                                             const float* __restrict__ W2,
                                             const float* __restrict__ b2,
                                             float* __restrict__ out) {
    int g = blockIdx.x;
    int c = threadIdx.x;
    __shared__ float pg[64], p[64];
    pg[c] = pooled2[g * DD + c];
    __syncthreads();
    float a = b1[c];
#pragma unroll 8
    for (int kk = 0; kk < 64; kk++) a += pg[kk] * W1[kk * DD + c];
    p[c] = fmaxf(a, 0.f);
    __syncthreads();
    if (c < 10) {
        float o = b2[c];
#pragma unroll 8
        for (int kk = 0; kk < 64; kk++) o += p[kk] * W2[kk * 10 + c];
        out[g * 10 + c] = o;
    }
}

// ---------------- launch ----------------

extern "C" void kernel_launch(void* const* d_in, const int* in_sizes, int n_in,
                              void* d_out, int out_size, void* d_ws, size_t ws_size,
                              hipStream_t stream) {
    const float* x    = (const float*)d_in[0];
    const int*   ei   = (const int*)d_in[1];
    const int*   batch= (const int*)d_in[2];
    const float* Wq   = (const float*)d_in[3];
    const float* bq   = (const float*)d_in[4];
    const float* Wk   = (const float*)d_in[5];
    const float* bk   = (const float*)d_in[6];
    const float* Wv   = (const float*)d_in[7];
    const float* bv   = (const float*)d_in[8];
    const float* Wsp  = (const float*)d_in[9];
    const float* bsp  = (const float*)d_in[10];
    const float* W1   = (const float*)d_in[11];
    const float* b1   = (const float*)d_in[12];
    const float* W2   = (const float*)d_in[13];
    const float* b2   = (const float*)d_in[14];
    float* out = (float*)d_out;
    float* pooled = out + NG * 10;

    const int* srcv = ei;
    const int* dstv = ei + NE;

    const size_t NEL = (size_t)NN * DD;
    ushort_t* hbf = (ushort_t*)d_ws;
    ushort_t* qb  = hbf + NEL;
    ushort_t* kb  = qb  + NEL;
    ushort_t* vb  = kb  + NEL;
    ushort_t* skb = vb  + NEL;
    int* rowstart = (int*)(skb + NEL);
    int* deg      = rowstart + (NN + 1);
    int* cursor   = deg + NN;
    int* csr_src  = cursor + NN;
    int* bsum     = csr_src + NE;

    int nbN = (NN + 255) / 256;

    zero_k<<<(2 * NN + 255) / 256, 256, 0, stream>>>(deg, 2 * NN);
    hist_k<<<(NE + 255) / 256, 256, 0, stream>>>(dstv, deg);
    scan1_k<<<nbN, 256, 0, stream>>>(deg, bsum);
    scan2_k<<<1, 1, 0, stream>>>(bsum, rowstart, nbN);
    scan3_k<<<nbN, 256, 0, stream>>>(deg, bsum, rowstart);
    scatter_k<<<(NE + 255) / 256, 256, 0, stream>>>(srcv, dstv, rowstart, cursor, csr_src);

    cvt_k<<<((int)NEL / 4 + 255) / 256, 256, 0, stream>>>(x, hbf, (int)NEL);

    int gtiles = (NN + 63) / 64;
    for (int l = 0; l < NL; l++) {
        gemm4_k<<<gtiles, 256, 0, stream>>>(hbf,
                                            Wq + l * DD * DD, bq + l * DD,
                                            Wk + l * DD * DD, bk + l * DD,
                                            Wv + l * DD * DD, bv + l * DD,
                                            Wsp + l * DD * DD, bsp + l * DD,
                                            qb, kb, vb, skb);
        agg_k<<<(NN * 64) / 256, 256, 0, stream>>>(qb, kb, vb, skb, rowstart, csr_src, hbf);
        pool_k<<<NG, 256, 0, stream>>>(hbf, batch, pooled + l * NG * DD);
    }
    head_k<<<NG, 64, 0, stream>>>(pooled + 2 * NG * DD, W1, b1, W2, b2, out);
}

// Round 3
// 389.954 us; speedup vs baseline: 3.0222x; 1.8418x over previous
//
#include <hip/hip_runtime.h>
#include <hip/hip_bf16.h>
#include <math.h>

#define NN 100000
#define NE 1000000
#define DD 64
#define NG 128
#define NL 3

typedef unsigned short ushort_t;
typedef __attribute__((ext_vector_type(8))) short short8v;
typedef __attribute__((ext_vector_type(4))) float f32x4;

__device__ __forceinline__ ushort_t f2bf(float f) {
    __hip_bfloat16 h = __float2bfloat16(f);
    return *reinterpret_cast<ushort_t*>(&h);
}
__device__ __forceinline__ float bf2f(ushort_t u) {
    unsigned v = ((unsigned)u) << 16;
    return __builtin_bit_cast(float, v);
}

// ---------------- CSR build ----------------

__global__ void zero_k(int* a, int n) {
    int i = blockIdx.x * blockDim.x + threadIdx.x;
    if (i < n) a[i] = 0;
}

__global__ void zerof_k(float* a, int n) {
    int i = blockIdx.x * blockDim.x + threadIdx.x;
    if (i < n) a[i] = 0.f;
}

__global__ void hist_k(const int* __restrict__ dst, int* __restrict__ deg) {
    int e = blockIdx.x * blockDim.x + threadIdx.x;
    if (e < NE) atomicAdd(&deg[dst[e]], 1);
}

__global__ void scan1_k(const int* __restrict__ deg, int* __restrict__ bsum) {
    int i = blockIdx.x * 256 + threadIdx.x;
    int v = (i < NN) ? deg[i] : 0;
#pragma unroll
    for (int off = 32; off; off >>= 1) v += __shfl_xor(v, off);
    __shared__ int s[4];
    if ((threadIdx.x & 63) == 0) s[threadIdx.x >> 6] = v;
    __syncthreads();
    if (threadIdx.x == 0) bsum[blockIdx.x] = s[0] + s[1] + s[2] + s[3];
}

// parallel exclusive scan over block sums (nb <= 512), one block of 512
__global__ __launch_bounds__(512) void scan2_k(int* bsum, int* rowstart, int nb) {
    __shared__ int wsum[8];
    int t = threadIdx.x;
    int lane = t & 63;
    int v = (t < nb) ? bsum[t] : 0;
    int inc = v;
#pragma unroll
    for (int off = 1; off < 64; off <<= 1) {
        int u = __shfl_up(inc, off);
        if (lane >= off) inc += u;
    }
    if (lane == 63) wsum[t >> 6] = inc;
    __syncthreads();
    if (t == 0) {
        int run = 0;
#pragma unroll
        for (int w = 0; w < 8; w++) { int x = wsum[w]; wsum[w] = run; run += x; }
    }
    __syncthreads();
    int excl = inc - v + wsum[t >> 6];
    if (t < nb) bsum[t] = excl;
    if (t == nb - 1) rowstart[NN] = excl + v;
}

__global__ void scan3_k(const int* __restrict__ deg, const int* __restrict__ bsum,
                        int* __restrict__ rowstart) {
    __shared__ int tmp[256];
    int t = threadIdx.x;
    int i = blockIdx.x * 256 + t;
    int v = (i < NN) ? deg[i] : 0;
    tmp[t] = v;
    __syncthreads();
#pragma unroll
    for (int off = 1; off < 256; off <<= 1) {
        int add = (t >= off) ? tmp[t - off] : 0;
        __syncthreads();
        tmp[t] += add;
        __syncthreads();
    }
    if (i < NN) rowstart[i] = tmp[t] - v + bsum[blockIdx.x];
}

__global__ void scatter_k(const int* __restrict__ src, const int* __restrict__ dst,
                          const int* __restrict__ rowstart, int* __restrict__ cursor,
                          int* __restrict__ csr_src) {
    int e = blockIdx.x * blockDim.x + threadIdx.x;
    if (e < NE) {
        int d = dst[e];
        int pos = atomicAdd(&cursor[d], 1);
        csr_src[rowstart[d] + pos] = src[e];
    }
}

// ---------------- f32 -> bf16 convert ----------------

__global__ void cvt_k(const float* __restrict__ x, ushort_t* __restrict__ o, int n) {
    int i = blockIdx.x * blockDim.x + threadIdx.x;
    int base = i * 4;
    if (base + 3 < n) {
        float4 v = *(const float4*)&x[base];
        o[base + 0] = f2bf(v.x); o[base + 1] = f2bf(v.y);
        o[base + 2] = f2bf(v.z); o[base + 3] = f2bf(v.w);
    } else {
        for (int k = base; k < n; k++) o[k] = f2bf(x[k]);
    }
}

// ---------------- W pre-pack into MFMA B-fragment layout ----------------
// blockIdx.x = layer*4 + mat; 64 threads.
// frag elem j for (ct,ks,lane): B[k][n], k=ks*32+lq*8+j, n=ct*16+ln

__global__ __launch_bounds__(64) void packw_k(const float* __restrict__ Wq,
                                              const float* __restrict__ Wk,
                                              const float* __restrict__ Wv,
                                              const float* __restrict__ Ws_,
                                              ushort_t* __restrict__ wpack) {
    int mat = blockIdx.x & 3, layer = blockIdx.x >> 2;
    const float* W = ((mat == 0) ? Wq : (mat == 1) ? Wk : (mat == 2) ? Wv : Ws_) + layer * DD * DD;
    int lane = threadIdx.x;
    int lq = lane >> 4, ln = lane & 15;
#pragma unroll
    for (int ct = 0; ct < 4; ct++) {
#pragma unroll
        for (int ks = 0; ks < 2; ks++) {
#pragma unroll
            for (int j = 0; j < 8; j++) {
                float v = W[(ks * 32 + lq * 8 + j) * DD + ct * 16 + ln];
                wpack[((size_t)(blockIdx.x * 8 + ct * 2 + ks)) * 512 + lane * 8 + j] = f2bf(v);
            }
        }
    }
}

// ---------------- fused 4-matrix MFMA GEMM ----------------

__global__ __launch_bounds__(256) void gemm4_k(const ushort_t* __restrict__ hbf,
                                               const ushort_t* __restrict__ wpl,  // layer's packed W
                                               const float* __restrict__ bq_, const float* __restrict__ bk_,
                                               const float* __restrict__ bv_, const float* __restrict__ bs_,
                                               ushort_t* __restrict__ qo, ushort_t* __restrict__ ko,
                                               ushort_t* __restrict__ vo, ushort_t* __restrict__ so) {
    __shared__ ushort_t sa[64][72];
    int t = threadIdx.x;
    int rowbase = blockIdx.x * 64;
    int lane = t & 63;
    int wv = t >> 6;
    int ln = lane & 15;
    int lq = lane >> 4;

#pragma unroll
    for (int it = 0; it < 2; ++it) {
        int lin = it * 256 + t;
        int r = lin >> 3;
        int c8 = (lin & 7) * 8;
        int grow = rowbase + r;
        short8v val = (short8v)0;
        if (grow < NN) val = *(const short8v*)&hbf[(size_t)grow * DD + c8];
        *(short8v*)&sa[r][c8] = val;
    }

    const float* bsel = (wv == 0) ? bq_ : (wv == 1) ? bk_ : (wv == 2) ? bv_ : bs_;
    ushort_t* osel    = (wv == 0) ? qo : (wv == 1) ? ko : (wv == 2) ? vo : so;

    short8v bfrag[4][2];
#pragma unroll
    for (int ct = 0; ct < 4; ct++) {
#pragma unroll
        for (int ks = 0; ks < 2; ks++) {
            bfrag[ct][ks] = *(const short8v*)&wpl[((size_t)(wv * 8 + ct * 2 + ks)) * 512 + lane * 8];
        }
    }
    float bias[4];
#pragma unroll
    for (int ct = 0; ct < 4; ct++) bias[ct] = bsel[ct * 16 + ln];

    __syncthreads();

#pragma unroll
    for (int rt = 0; rt < 4; rt++) {
        short8v a0 = *(const short8v*)&sa[rt * 16 + ln][lq * 8];
        short8v a1 = *(const short8v*)&sa[rt * 16 + ln][32 + lq * 8];
#pragma unroll
        for (int ct = 0; ct < 4; ct++) {
            f32x4 acc;
            acc[0] = bias[ct]; acc[1] = bias[ct]; acc[2] = bias[ct]; acc[3] = bias[ct];
            acc = __builtin_amdgcn_mfma_f32_16x16x32_bf16(a0, bfrag[ct][0], acc, 0, 0, 0);
            acc = __builtin_amdgcn_mfma_f32_16x16x32_bf16(a1, bfrag[ct][1], acc, 0, 0, 0);
#pragma unroll
            for (int i = 0; i < 4; i++) {
                int grow = rowbase + rt * 16 + lq * 4 + i;
                if (grow < NN) osel[(size_t)grow * DD + ct * 16 + ln] = f2bf(acc[i]);
            }
        }
    }
}

// ---------------- single-pass online-softmax aggregate + skip + relu ----------------
// One wave per node. 4 groups of 16 lanes; group g handles edge jb+g; lane l holds dims 4l..4l+3.

__global__ __launch_bounds__(256) void agg_k(const ushort_t* __restrict__ qb,
                                             const ushort_t* __restrict__ kb,
                                             const ushort_t* __restrict__ vb,
                                             const ushort_t* __restrict__ skb,
                                             const int* __restrict__ rowstart,
                                             const int* __restrict__ csr_src,
                                             ushort_t* __restrict__ hout) {
    int wv = threadIdx.x >> 6;
    int nid = blockIdx.x * 4 + wv;
    if (nid >= NN) return;
    int lane = threadIdx.x & 63;
    int g = lane >> 4, l = lane & 15;
    int r0 = rowstart[nid], r1 = rowstart[nid + 1];

    ushort4 qu = *(const ushort4*)&qb[(size_t)nid * DD + 4 * l];
    float q0 = bf2f(qu.x), q1 = bf2f(qu.y), q2 = bf2f(qu.z), q3 = bf2f(qu.w);

    float m = -3.0e38f, se = 0.f;
    float a0 = 0.f, a1 = 0.f, a2 = 0.f, a3 = 0.f;

    // prefetch first edge
    int e0 = r0 + g;
    bool act0 = e0 < r1;
    int s0 = act0 ? csr_src[e0] : 0;
    ushort4 ku0 = *(const ushort4*)&kb[(size_t)s0 * DD + 4 * l];
    ushort4 vu0 = *(const ushort4*)&vb[(size_t)s0 * DD + 4 * l];

    for (int jb = r0; jb < r1; jb += 4) {
        // prefetch next
        int e1 = jb + 4 + g;
        bool act1 = e1 < r1;
        int s1 = act1 ? csr_src[e1] : 0;
        ushort4 ku1 = *(const ushort4*)&kb[(size_t)s1 * DD + 4 * l];
        ushort4 vu1 = *(const ushort4*)&vb[(size_t)s1 * DD + 4 * l];

        // dot over 64 dims: 4 per lane, reduce over 16 lanes of the group
        float dp = q0 * bf2f(ku0.x) + q1 * bf2f(ku0.y) + q2 * bf2f(ku0.z) + q3 * bf2f(ku0.w);
        dp += __shfl_xor(dp, 1);
        dp += __shfl_xor(dp, 2);
        dp += __shfl_xor(dp, 4);
        dp += __shfl_xor(dp, 8);

        float w = 0.f;
        if (act0) {
            float sc = dp * 0.125f;
            if (sc <= m + 8.0f) {
                w = __expf(sc - m);
            } else {  // rare rescale (first edge, or max jumped by >8)
                float c = __expf(m - sc);
                se *= c; a0 *= c; a1 *= c; a2 *= c; a3 *= c;
                m = sc; w = 1.0f;
            }
        }
        se += w;
        a0 += w * bf2f(vu0.x);
        a1 += w * bf2f(vu0.y);
        a2 += w * bf2f(vu0.z);
        a3 += w * bf2f(vu0.w);

        act0 = act1; ku0 = ku1; vu0 = vu1;
    }

    // flash-style cross-group combine
    float M = m;
    M = fmaxf(M, __shfl_xor(M, 16));
    M = fmaxf(M, __shfl_xor(M, 32));
    float c = __expf(m - M);  // m==M==-3e38 -> 1, but se/acc are 0 then
    se *= c; a0 *= c; a1 *= c; a2 *= c; a3 *= c;
    se += __shfl_xor(se, 16); se += __shfl_xor(se, 32);
    a0 += __shfl_xor(a0, 16); a0 += __shfl_xor(a0, 32);
    a1 += __shfl_xor(a1, 16); a1 += __shfl_xor(a1, 32);
    a2 += __shfl_xor(a2, 16); a2 += __shfl_xor(a2, 32);
    a3 += __shfl_xor(a3, 16); a3 += __shfl_xor(a3, 32);

    if (g == 0) {
        float inv = 1.0f / (se + 1e-16f);
        ushort4 su = *(const ushort4*)&skb[(size_t)nid * DD + 4 * l];
        ushort4 ou;
        ou.x = f2bf(fmaxf(a0 * inv + bf2f(su.x), 0.f));
        ou.y = f2bf(fmaxf(a1 * inv + bf2f(su.y), 0.f));
        ou.z = f2bf(fmaxf(a2 * inv + bf2f(su.z), 0.f));
        ou.w = f2bf(fmaxf(a3 * inv + bf2f(su.w), 0.f));
        *(ushort4*)&hout[(size_t)nid * DD + 4 * l] = ou;
    }
}

// ---------------- global add pool: chunked blocks + segment atomics ----------------

#define POOL_ROWS 128

__global__ __launch_bounds__(256) void pool_k(const ushort_t* __restrict__ h,
                                              const int* __restrict__ batch,
                                              float* __restrict__ pooled) {
    int i0 = blockIdx.x * POOL_ROWS;
    int i1 = i0 + POOL_ROWS; if (i1 > NN) i1 = NN;
    int lane = threadIdx.x & 63;
    int wv = threadIdx.x >> 6;
    float acc = 0.f;
    int gcur = -1;
    for (int i = i0 + wv; i < i1; i += 4) {
        int gi = batch[i];  // wave-uniform (sorted)
        if (gi != gcur) {
            if (gcur >= 0) atomicAdd(&pooled[gcur * DD + lane], acc);
            gcur = gi; acc = 0.f;
        }
        acc += bf2f(h[(size_t)i * DD + lane]);
    }
    if (gcur >= 0) atomicAdd(&pooled[gcur * DD + lane], acc);
}

// ---------------- head ----------------

__global__ __launch_bounds__(64) void head_k(const float* __restrict__ pooled2,
                                             const float* __restrict__ W1,
                                             const float* __restrict__ b1,
                                             const float* __restrict__ W2,
                                             const float* __restrict__ b2,
                                             float* __restrict__ out) {
    int g = blockIdx.x;
    int c = threadIdx.x;
    __shared__ float pg[64], p[64];
    pg[c] = pooled2[g * DD + c];
    __syncthreads();
    float a = b1[c];
#pragma unroll 8
    for (int kk = 0; kk < 64; kk++) a += pg[kk] * W1[kk * DD + c];
    p[c] = fmaxf(a, 0.f);
    __syncthreads();
    if (c < 10) {
        float o = b2[c];
#pragma unroll 8
        for (int kk = 0; kk < 64; kk++) o += p[kk] * W2[kk * 10 + c];
        out[g * 10 + c] = o;
    }
}

// ---------------- launch ----------------

extern "C" void kernel_launch(void* const* d_in, const int* in_sizes, int n_in,
                              void* d_out, int out_size, void* d_ws, size_t ws_size,
                              hipStream_t stream) {
    const float* x    = (const float*)d_in[0];
    const int*   ei   = (const int*)d_in[1];
    const int*   batch= (const int*)d_in[2];
    const float* Wq   = (const float*)d_in[3];
    const float* bq   = (const float*)d_in[4];
    const float* Wk   = (const float*)d_in[5];
    const float* bk   = (const float*)d_in[6];
    const float* Wv   = (const float*)d_in[7];
    const float* bv   = (const float*)d_in[8];
    const float* Wsp  = (const float*)d_in[9];
    const float* bsp  = (const float*)d_in[10];
    const float* W1   = (const float*)d_in[11];
    const float* b1   = (const float*)d_in[12];
    const float* W2   = (const float*)d_in[13];
    const float* b2   = (const float*)d_in[14];
    float* out = (float*)d_out;
    float* pooled = out + NG * 10;

    const int* srcv = ei;
    const int* dstv = ei + NE;

    const size_t NEL = (size_t)NN * DD;
    ushort_t* hbf = (ushort_t*)d_ws;
    ushort_t* qb  = hbf + NEL;
    ushort_t* kb  = qb  + NEL;
    ushort_t* vb  = kb  + NEL;
    ushort_t* skb = vb  + NEL;
    int* rowstart = (int*)(skb + NEL);
    int* deg      = rowstart + (NN + 1);
    int* cursor   = deg + NN;
    int* csr_src  = cursor + NN;
    int* bsum     = csr_src + NE;
    ushort_t* wpack = (ushort_t*)(bsum + 512);  // 12 mats * 4096 bf16

    int nbN = (NN + 255) / 256;
    int totOut = NG * 10 + NL * NG * DD;

    zero_k<<<(2 * NN + 255) / 256, 256, 0, stream>>>(deg, 2 * NN);
    zerof_k<<<(totOut + 255) / 256, 256, 0, stream>>>(out, totOut);
    hist_k<<<(NE + 255) / 256, 256, 0, stream>>>(dstv, deg);
    scan1_k<<<nbN, 256, 0, stream>>>(deg, bsum);
    scan2_k<<<1, 512, 0, stream>>>(bsum, rowstart, nbN);
    scan3_k<<<nbN, 256, 0, stream>>>(deg, bsum, rowstart);
    scatter_k<<<(NE + 255) / 256, 256, 0, stream>>>(srcv, dstv, rowstart, cursor, csr_src);

    cvt_k<<<((int)NEL / 4 + 255) / 256, 256, 0, stream>>>(x, hbf, (int)NEL);
    packw_k<<<NL * 4, 64, 0, stream>>>(Wq, Wk, Wv, Wsp, wpack);

    int gtiles = (NN + 63) / 64;
    int poolblocks = (NN + POOL_ROWS - 1) / POOL_ROWS;
    for (int l = 0; l < NL; l++) {
        gemm4_k<<<gtiles, 256, 0, stream>>>(hbf, wpack + (size_t)l * 4 * 8 * 512,
                                            bq + l * DD, bk + l * DD, bv + l * DD, bsp + l * DD,
                                            qb, kb, vb, skb);
        agg_k<<<(NN + 3) / 4, 256, 0, stream>>>(qb, kb, vb, skb, rowstart, csr_src, hbf);
        pool_k<<<poolblocks, 256, 0, stream>>>(hbf, batch, pooled + l * NG * DD);
    }
    head_k<<<NG, 64, 0, stream>>>(pooled + 2 * NG * DD, W1, b1, W2, b2, out);
}

// Round 4
// 310.842 us; speedup vs baseline: 3.7914x; 1.2545x over previous
//
#include <hip/hip_runtime.h>
#include <hip/hip_bf16.h>
#include <math.h>

#define NN 100000
#define NE 1000000
#define DD 64
#define NG 128
#define NL 3

#define NBUK 196          // dst >> 9 buckets (512 nodes each)
#define EPB 2048          // edges per bin block
#define NBLK ((NE + EPB - 1) / EPB)   // 489
#define BCAP 6144         // per-bucket pair capacity in LDS (mean 5120, 14 sigma margin)

typedef unsigned short ushort_t;
typedef unsigned long long u64;
typedef __attribute__((ext_vector_type(8))) short short8v;
typedef __attribute__((ext_vector_type(4))) float f32x4;

__device__ __forceinline__ ushort_t f2bf(float f) {
    __hip_bfloat16 h = __float2bfloat16(f);
    return *reinterpret_cast<ushort_t*>(&h);
}
__device__ __forceinline__ float bf2f(ushort_t u) {
    unsigned v = ((unsigned)u) << 16;
    return __builtin_bit_cast(float, v);
}

// ---------------- misc ----------------

__global__ void zerof_k(float* a, int n) {
    int i = blockIdx.x * blockDim.x + threadIdx.x;
    if (i < n) a[i] = 0.f;
}

__global__ void cvt_k(const float* __restrict__ x, ushort_t* __restrict__ o, int n) {
    int i = blockIdx.x * blockDim.x + threadIdx.x;
    int base = i * 4;
    if (base + 3 < n) {
        float4 v = *(const float4*)&x[base];
        o[base + 0] = f2bf(v.x); o[base + 1] = f2bf(v.y);
        o[base + 2] = f2bf(v.z); o[base + 3] = f2bf(v.w);
    } else {
        for (int k = base; k < n; k++) o[k] = f2bf(x[k]);
    }
}

// ---------------- CSR build: block-local bucket sort ----------------
// K1: each block sorts EPB edges by bucket in LDS, writes pairs sequentially.

__global__ __launch_bounds__(256) void bin_k(const int* __restrict__ src,
                                             const int* __restrict__ dst,
                                             u64* __restrict__ binbuf,
                                             int* __restrict__ counts,     // [NBUK][NBLK]
                                             int* __restrict__ localoff) { // [NBUK][NBLK]
    __shared__ int hist[NBUK];
    __shared__ int excl[NBUK];
    __shared__ int cur[NBUK];
    __shared__ int tmp[256];
    __shared__ u64 pairs[EPB];
    int t = threadIdx.x;
    int blk = blockIdx.x;
    int e0 = blk * EPB;
    int totvalid = NE - e0; if (totvalid > EPB) totvalid = EPB;

    for (int i = t; i < NBUK; i += 256) hist[i] = 0;
    __syncthreads();

    int mysrc[8], mydst[8];
#pragma unroll
    for (int i = 0; i < 8; i++) {
        int e = e0 + i * 256 + t;
        bool v = e < NE;
        mysrc[i] = v ? src[e] : -1;
        mydst[i] = v ? dst[e] : -1;
        if (v) atomicAdd(&hist[mydst[i] >> 9], 1);
    }
    __syncthreads();

    int v = (t < NBUK) ? hist[t] : 0;
    tmp[t] = v;
    __syncthreads();
#pragma unroll
    for (int off = 1; off < 256; off <<= 1) {
        int a = (t >= off) ? tmp[t - off] : 0;
        __syncthreads();
        tmp[t] += a;
        __syncthreads();
    }
    if (t < NBUK) { excl[t] = tmp[t] - v; cur[t] = tmp[t] - v; }
    __syncthreads();

#pragma unroll
    for (int i = 0; i < 8; i++) {
        if (mydst[i] >= 0) {
            int b = mydst[i] >> 9;
            int p = atomicAdd(&cur[b], 1);
            pairs[p] = ((u64)(unsigned)mydst[i] << 32) | (unsigned)mysrc[i];
        }
    }
    __syncthreads();

    for (int i = t; i < totvalid; i += 256) binbuf[(size_t)blk * EPB + i] = pairs[i];
    if (t < NBUK) {
        counts[t * NBLK + blk] = hist[t];
        localoff[t * NBLK + blk] = excl[t];
    }
}

// K2a: per bucket, exclusive scan over block chunks -> chunkoff; total -> buktot.

__global__ __launch_bounds__(256) void scanA_k(const int* __restrict__ counts,
                                               int* __restrict__ chunkoff,
                                               int* __restrict__ buktot) {
    __shared__ int tmp[512];
    int b = blockIdx.x;
    int t = threadIdx.x;
    int v0 = (t < NBLK) ? counts[b * NBLK + t] : 0;
    int v1 = (256 + t < NBLK) ? counts[b * NBLK + 256 + t] : 0;
    tmp[t] = v0; tmp[t + 256] = v1;
    __syncthreads();
#pragma unroll
    for (int off = 1; off < 512; off <<= 1) {
        int a0 = (t >= off) ? tmp[t - off] : 0;
        int i1 = t + 256;
        int a1 = (i1 >= off) ? tmp[i1 - off] : 0;
        __syncthreads();
        tmp[t] += a0; tmp[i1] += a1;
        __syncthreads();
    }
    if (t < NBLK) chunkoff[b * NBLK + t] = tmp[t] - v0;
    if (256 + t < NBLK) chunkoff[b * NBLK + 256 + t] = tmp[t + 256] - v1;
    if (t == 0) buktot[b] = tmp[511];
}

// K2b: scan bucket totals -> bukbase; rowstart[NN] = NE.

__global__ __launch_bounds__(256) void scanB_k(const int* __restrict__ buktot,
                                               int* __restrict__ bukbase,
                                               int* __restrict__ rowstart) {
    __shared__ int tmp[256];
    int t = threadIdx.x;
    int v = (t < NBUK) ? buktot[t] : 0;
    tmp[t] = v;
    __syncthreads();
#pragma unroll
    for (int off = 1; off < 256; off <<= 1) {
        int a = (t >= off) ? tmp[t - off] : 0;
        __syncthreads();
        tmp[t] += a;
        __syncthreads();
    }
    if (t < NBUK) bukbase[t] = tmp[t] - v;
    if (t == 0) rowstart[NN] = NE;
}

// K3: per bucket: gather pairs, deg-hist, scan, write rowstart + csr sequentially.

__global__ __launch_bounds__(256) void csr_k(const u64* __restrict__ binbuf,
                                             const int* __restrict__ counts,
                                             const int* __restrict__ localoff,
                                             const int* __restrict__ chunkoff,
                                             const int* __restrict__ bukbase,
                                             int* __restrict__ rowstart,
                                             int* __restrict__ csr_src) {
    __shared__ u64 pairs[BCAP];
    __shared__ int csrb[BCAP];
    __shared__ int deg[512];
    __shared__ int excl[512];
    __shared__ int cur[512];
    __shared__ int tmp[512];
    int b = blockIdx.x;
    int t = threadIdx.x;
    int base = bukbase[b];
    int nbase = b << 9;
    int T = chunkoff[b * NBLK + NBLK - 1] + counts[b * NBLK + NBLK - 1];
    bool fits = (T <= BCAP);

    for (int i = t; i < 512; i += 256) deg[i] = 0;

    if (fits) {
        for (int blk = t; blk < NBLK; blk += 256) {
            int c = counts[b * NBLK + blk];
            int lo = localoff[b * NBLK + blk];
            int o = chunkoff[b * NBLK + blk];
            for (int i = 0; i < c; i++) pairs[o + i] = binbuf[(size_t)blk * EPB + lo + i];
        }
        __syncthreads();
        for (int i = t; i < T; i += 256) {
            int d = (int)(pairs[i] >> 32);
            atomicAdd(&deg[d - nbase], 1);
        }
    } else {  // fallback (never for this input size, kept for safety)
        __syncthreads();
        for (int blk = 0; blk < NBLK; blk++) {
            int c = counts[b * NBLK + blk];
            int lo = localoff[b * NBLK + blk];
            for (int i = t; i < c; i += 256) {
                int d = (int)(binbuf[(size_t)blk * EPB + lo + i] >> 32);
                atomicAdd(&deg[d - nbase], 1);
            }
        }
    }
    __syncthreads();

    int v0 = deg[t], v1 = deg[t + 256];
    tmp[t] = v0; tmp[t + 256] = v1;
    __syncthreads();
#pragma unroll
    for (int off = 1; off < 512; off <<= 1) {
        int a0 = (t >= off) ? tmp[t - off] : 0;
        int i1 = t + 256;
        int a1 = (i1 >= off) ? tmp[i1 - off] : 0;
        __syncthreads();
        tmp[t] += a0; tmp[i1] += a1;
        __syncthreads();
    }
    excl[t] = tmp[t] - v0; excl[t + 256] = tmp[t + 256] - v1;
    cur[t] = excl[t]; cur[t + 256] = excl[t + 256];
    __syncthreads();

    for (int i = t; i < 512; i += 256) {
        int n = nbase + i;
        if (n < NN) rowstart[n] = base + excl[i];
    }

    if (fits) {
        for (int i = t; i < T; i += 256) {
            u64 p = pairs[i];
            int d = (int)(p >> 32);
            int pos = atomicAdd(&cur[d - nbase], 1);
            csrb[pos] = (int)(p & 0xffffffffu);
        }
        __syncthreads();
        for (int i = t; i < T; i += 256) csr_src[base + i] = csrb[i];
    } else {
        for (int blk = 0; blk < NBLK; blk++) {
            int c = counts[b * NBLK + blk];
            int lo = localoff[b * NBLK + blk];
            for (int i = t; i < c; i += 256) {
                u64 p = binbuf[(size_t)blk * EPB + lo + i];
                int d = (int)(p >> 32);
                int pos = atomicAdd(&cur[d - nbase], 1);
                csr_src[base + pos] = (int)(p & 0xffffffffu);
            }
        }
    }
}

// ---------------- W pre-pack into MFMA B-fragment layout ----------------

__global__ __launch_bounds__(64) void packw_k(const float* __restrict__ Wq,
                                              const float* __restrict__ Wk,
                                              const float* __restrict__ Wv,
                                              const float* __restrict__ Ws_,
                                              ushort_t* __restrict__ wpack) {
    int mat = blockIdx.x & 3, layer = blockIdx.x >> 2;
    const float* W = ((mat == 0) ? Wq : (mat == 1) ? Wk : (mat == 2) ? Wv : Ws_) + layer * DD * DD;
    int lane = threadIdx.x;
    int lq = lane >> 4, ln = lane & 15;
#pragma unroll
    for (int ct = 0; ct < 4; ct++) {
#pragma unroll
        for (int ks = 0; ks < 2; ks++) {
#pragma unroll
            for (int j = 0; j < 8; j++) {
                float v = W[(ks * 32 + lq * 8 + j) * DD + ct * 16 + ln];
                wpack[((size_t)(blockIdx.x * 8 + ct * 2 + ks)) * 512 + lane * 8 + j] = f2bf(v);
            }
        }
    }
}

// ---------------- fused 4-matrix MFMA GEMM (kv interleaved output) ----------------

__global__ __launch_bounds__(256) void gemm4_k(const ushort_t* __restrict__ hbf,
                                               const ushort_t* __restrict__ wpl,
                                               const float* __restrict__ bq_, const float* __restrict__ bk_,
                                               const float* __restrict__ bv_, const float* __restrict__ bs_,
                                               ushort_t* __restrict__ qo, ushort_t* __restrict__ kvo,
                                               ushort_t* __restrict__ so) {
    __shared__ ushort_t sa[64][72];
    int t = threadIdx.x;
    int rowbase = blockIdx.x * 64;
    int lane = t & 63;
    int wv = t >> 6;
    int ln = lane & 15;
    int lq = lane >> 4;

#pragma unroll
    for (int it = 0; it < 2; ++it) {
        int lin = it * 256 + t;
        int r = lin >> 3;
        int c8 = (lin & 7) * 8;
        int grow = rowbase + r;
        short8v val = (short8v)0;
        if (grow < NN) val = *(const short8v*)&hbf[(size_t)grow * DD + c8];
        *(short8v*)&sa[r][c8] = val;
    }

    const float* bsel = (wv == 0) ? bq_ : (wv == 1) ? bk_ : (wv == 2) ? bv_ : bs_;

    short8v bfrag[4][2];
#pragma unroll
    for (int ct = 0; ct < 4; ct++) {
#pragma unroll
        for (int ks = 0; ks < 2; ks++) {
            bfrag[ct][ks] = *(const short8v*)&wpl[((size_t)(wv * 8 + ct * 2 + ks)) * 512 + lane * 8];
        }
    }
    float bias[4];
#pragma unroll
    for (int ct = 0; ct < 4; ct++) bias[ct] = bsel[ct * 16 + ln];

    __syncthreads();

#pragma unroll
    for (int rt = 0; rt < 4; rt++) {
        short8v a0 = *(const short8v*)&sa[rt * 16 + ln][lq * 8];
        short8v a1 = *(const short8v*)&sa[rt * 16 + ln][32 + lq * 8];
#pragma unroll
        for (int ct = 0; ct < 4; ct++) {
            f32x4 acc;
            acc[0] = bias[ct]; acc[1] = bias[ct]; acc[2] = bias[ct]; acc[3] = bias[ct];
            acc = __builtin_amdgcn_mfma_f32_16x16x32_bf16(a0, bfrag[ct][0], acc, 0, 0, 0);
            acc = __builtin_amdgcn_mfma_f32_16x16x32_bf16(a1, bfrag[ct][1], acc, 0, 0, 0);
            int col = ct * 16 + ln;
#pragma unroll
            for (int i = 0; i < 4; i++) {
                int grow = rowbase + rt * 16 + lq * 4 + i;
                if (grow < NN) {
                    float fv = acc[i];
                    if (wv == 0)      qo[(size_t)grow * DD + col] = f2bf(fv);
                    else if (wv == 3) so[(size_t)grow * DD + col] = f2bf(fv);
                    else              kvo[(size_t)grow * 2 * DD + 2 * col + (wv - 1)] = f2bf(fv);
                }
            }
        }
    }
}

// ---------------- single-pass online-softmax aggregate + skip + relu ----------------
// One wave per node; 4 groups of 16 lanes, group g handles edge jb+g;
// lane l holds dims 4l..4l+3; kv interleaved -> one 16B gather per lane.

__global__ __launch_bounds__(256) void agg_k(const ushort_t* __restrict__ qb,
                                             const ushort_t* __restrict__ kvb,
                                             const ushort_t* __restrict__ skb,
                                             const int* __restrict__ rowstart,
                                             const int* __restrict__ csr_src,
                                             ushort_t* __restrict__ hout) {
    int wv = threadIdx.x >> 6;
    int nid = blockIdx.x * 4 + wv;
    if (nid >= NN) return;
    int lane = threadIdx.x & 63;
    int g = lane >> 4, l = lane & 15;
    int r0 = rowstart[nid], r1 = rowstart[nid + 1];

    ushort4 qu = *(const ushort4*)&qb[(size_t)nid * DD + 4 * l];
    float q0 = bf2f(qu.x), q1 = bf2f(qu.y), q2 = bf2f(qu.z), q3 = bf2f(qu.w);

    float m = -3.0e38f, se = 0.f;
    float a0 = 0.f, a1 = 0.f, a2 = 0.f, a3 = 0.f;

    int e0 = r0 + g;
    bool act0 = e0 < r1;
    int s0 = act0 ? csr_src[e0] : 0;
    short8v kv0 = *(const short8v*)&kvb[(size_t)s0 * 2 * DD + 8 * l];

    for (int jb = r0; jb < r1; jb += 4) {
        int e1 = jb + 4 + g;
        bool act1 = e1 < r1;
        int s1 = act1 ? csr_src[e1] : 0;
        short8v kv1 = *(const short8v*)&kvb[(size_t)s1 * 2 * DD + 8 * l];

        float dp = q0 * bf2f((ushort_t)kv0[0]) + q1 * bf2f((ushort_t)kv0[2])
                 + q2 * bf2f((ushort_t)kv0[4]) + q3 * bf2f((ushort_t)kv0[6]);
        dp += __shfl_xor(dp, 1);
        dp += __shfl_xor(dp, 2);
        dp += __shfl_xor(dp, 4);
        dp += __shfl_xor(dp, 8);

        float w = 0.f;
        if (act0) {
            float sc = dp * 0.125f;
            if (sc <= m + 8.0f) {
                w = __expf(sc - m);
            } else {
                float c = __expf(m - sc);
                se *= c; a0 *= c; a1 *= c; a2 *= c; a3 *= c;
                m = sc; w = 1.0f;
            }
        }
        se += w;
        a0 += w * bf2f((ushort_t)kv0[1]);
        a1 += w * bf2f((ushort_t)kv0[3]);
        a2 += w * bf2f((ushort_t)kv0[5]);
        a3 += w * bf2f((ushort_t)kv0[7]);

        act0 = act1; kv0 = kv1;
    }

    float M = m;
    M = fmaxf(M, __shfl_xor(M, 16));
    M = fmaxf(M, __shfl_xor(M, 32));
    float c = __expf(m - M);
    se *= c; a0 *= c; a1 *= c; a2 *= c; a3 *= c;
    se += __shfl_xor(se, 16); se += __shfl_xor(se, 32);
    a0 += __shfl_xor(a0, 16); a0 += __shfl_xor(a0, 32);
    a1 += __shfl_xor(a1, 16); a1 += __shfl_xor(a1, 32);
    a2 += __shfl_xor(a2, 16); a2 += __shfl_xor(a2, 32);
    a3 += __shfl_xor(a3, 16); a3 += __shfl_xor(a3, 32);

    if (g == 0) {
        float inv = 1.0f / (se + 1e-16f);
        ushort4 su = *(const ushort4*)&skb[(size_t)nid * DD + 4 * l];
        ushort4 ou;
        ou.x = f2bf(fmaxf(a0 * inv + bf2f(su.x), 0.f));
        ou.y = f2bf(fmaxf(a1 * inv + bf2f(su.y), 0.f));
        ou.z = f2bf(fmaxf(a2 * inv + bf2f(su.z), 0.f));
        ou.w = f2bf(fmaxf(a3 * inv + bf2f(su.w), 0.f));
        *(ushort4*)&hout[(size_t)nid * DD + 4 * l] = ou;
    }
}

// ---------------- global add pool ----------------

#define POOL_ROWS 128

__global__ __launch_bounds__(256) void pool_k(const ushort_t* __restrict__ h,
                                              const int* __restrict__ batch,
                                              float* __restrict__ pooled) {
    int i0 = blockIdx.x * POOL_ROWS;
    int i1 = i0 + POOL_ROWS; if (i1 > NN) i1 = NN;
    int lane = threadIdx.x & 63;
    int wv = threadIdx.x >> 6;
    float acc = 0.f;
    int gcur = -1;
    for (int i = i0 + wv; i < i1; i += 4) {
        int gi = batch[i];
        if (gi != gcur) {
            if (gcur >= 0) atomicAdd(&pooled[gcur * DD + lane], acc);
            gcur = gi; acc = 0.f;
        }
        acc += bf2f(h[(size_t)i * DD + lane]);
    }
    if (gcur >= 0) atomicAdd(&pooled[gcur * DD + lane], acc);
}

// ---------------- head ----------------

__global__ __launch_bounds__(64) void head_k(const float* __restrict__ pooled2,
                                             const float* __restrict__ W1,
                                             const float* __restrict__ b1,
                                             const float* __restrict__ W2,
                                             const float* __restrict__ b2,
                                             float* __restrict__ out) {
    int g = blockIdx.x;
    int c = threadIdx.x;
    __shared__ float pg[64], p[64];
    pg[c] = pooled2[g * DD + c];
    __syncthreads();
    float a = b1[c];
#pragma unroll 8
    for (int kk = 0; kk < 64; kk++) a += pg[kk] * W1[kk * DD + c];
    p[c] = fmaxf(a, 0.f);
    __syncthreads();
    if (c < 10) {
        float o = b2[c];
#pragma unroll 8
        for (int kk = 0; kk < 64; kk++) o += p[kk] * W2[kk * 10 + c];
        out[g * 10 + c] = o;
    }
}

// ---------------- launch ----------------

extern "C" void kernel_launch(void* const* d_in, const int* in_sizes, int n_in,
                              void* d_out, int out_size, void* d_ws, size_t ws_size,
                              hipStream_t stream) {
    const float* x    = (const float*)d_in[0];
    const int*   ei   = (const int*)d_in[1];
    const int*   batch= (const int*)d_in[2];
    const float* Wq   = (const float*)d_in[3];
    const float* bq   = (const float*)d_in[4];
    const float* Wk   = (const float*)d_in[5];
    const float* bk   = (const float*)d_in[6];
    const float* Wv   = (const float*)d_in[7];
    const float* bv   = (const float*)d_in[8];
    const float* Wsp  = (const float*)d_in[9];
    const float* bsp  = (const float*)d_in[10];
    const float* W1   = (const float*)d_in[11];
    const float* b1   = (const float*)d_in[12];
    const float* W2   = (const float*)d_in[13];
    const float* b2   = (const float*)d_in[14];
    float* out = (float*)d_out;
    float* pooled = out + NG * 10;

    const int* srcv = ei;
    const int* dstv = ei + NE;

    const size_t NEL = (size_t)NN * DD;
    ushort_t* hbf = (ushort_t*)d_ws;                 // [NN][64]
    ushort_t* qb  = hbf + NEL;                       // [NN][64]
    ushort_t* skb = qb  + NEL;                       // [NN][64]
    ushort_t* kvb = skb + NEL;                       // [NN][128]
    u64* binbuf   = (u64*)(kvb + 2 * NEL);           // [NBLK*EPB]
    int* counts   = (int*)(binbuf + (size_t)NBLK * EPB);  // [NBUK*NBLK]
    int* localoff = counts + NBUK * NBLK;
    int* chunkoff = localoff + NBUK * NBLK;
    int* buktot   = chunkoff + NBUK * NBLK;          // [NBUK]
    int* bukbase  = buktot + NBUK;                   // [NBUK]
    int* rowstart = bukbase + NBUK;                  // [NN+1]
    int* csr_src  = rowstart + (NN + 1);             // [NE]
    ushort_t* wpack = (ushort_t*)(csr_src + NE);     // 12*4096 bf16

    int totOut = NG * 10 + NL * NG * DD;

    zerof_k<<<(totOut + 255) / 256, 256, 0, stream>>>(out, totOut);
    cvt_k<<<((int)NEL / 4 + 255) / 256, 256, 0, stream>>>(x, hbf, (int)NEL);
    packw_k<<<NL * 4, 64, 0, stream>>>(Wq, Wk, Wv, Wsp, wpack);

    bin_k<<<NBLK, 256, 0, stream>>>(srcv, dstv, binbuf, counts, localoff);
    scanA_k<<<NBUK, 256, 0, stream>>>(counts, chunkoff, buktot);
    scanB_k<<<1, 256, 0, stream>>>(buktot, bukbase, rowstart);
    csr_k<<<NBUK, 256, 0, stream>>>(binbuf, counts, localoff, chunkoff, bukbase,
                                    rowstart, csr_src);

    int gtiles = (NN + 63) / 64;
    int poolblocks = (NN + POOL_ROWS - 1) / POOL_ROWS;
    for (int l = 0; l < NL; l++) {
        gemm4_k<<<gtiles, 256, 0, stream>>>(hbf, wpack + (size_t)l * 4 * 8 * 512,
                                            bq + l * DD, bk + l * DD, bv + l * DD, bsp + l * DD,
                                            qb, kvb, skb);
        agg_k<<<(NN + 3) / 4, 256, 0, stream>>>(qb, kvb, skb, rowstart, csr_src, hbf);
        pool_k<<<poolblocks, 256, 0, stream>>>(hbf, batch, pooled + l * NG * DD);
    }
    head_k<<<NG, 64, 0, stream>>>(pooled + 2 * NG * DD, W1, b1, W2, b2, out);
}

// Round 5
// 282.800 us; speedup vs baseline: 4.1674x; 1.0992x over previous
//
#include <hip/hip_runtime.h>
#include <hip/hip_bf16.h>
#include <math.h>

#define NN 100000
#define NE 1000000
#define DD 64
#define NG 128
#define NL 3

#define NBUK 196          // dst >> 9 buckets (512 nodes each)
#define EPB 2048          // edges per bin block
#define NBLK ((NE + EPB - 1) / EPB)   // 489
#define BCAP 6144         // per-bucket pair capacity in LDS

typedef unsigned short ushort_t;
typedef unsigned int u32;
typedef __attribute__((ext_vector_type(8))) short short8v;
typedef __attribute__((ext_vector_type(4))) float f32x4;
typedef __attribute__((ext_vector_type(4))) unsigned int u32x4;

__device__ __forceinline__ ushort_t f2bf(float f) {
    __hip_bfloat16 h = __float2bfloat16(f);
    return *reinterpret_cast<ushort_t*>(&h);
}
__device__ __forceinline__ float bf2f(ushort_t u) {
    unsigned v = ((unsigned)u) << 16;
    return __builtin_bit_cast(float, v);
}
__device__ __forceinline__ unsigned cvtpk(float lo, float hi) {
    unsigned r;
    asm("v_cvt_pk_bf16_f32 %0, %1, %2" : "=v"(r) : "v"(lo), "v"(hi));
    return r;
}
// sum over each 8-lane group (lanes grouped by lane>>3)
__device__ __forceinline__ float sum8(float x) {
    int v = __builtin_bit_cast(int, x);
    int t1 = __builtin_amdgcn_update_dpp(0, v, 0xB1, 0xF, 0xF, true);   // quad_perm xor1
    x += __builtin_bit_cast(float, t1);
    v = __builtin_bit_cast(int, x);
    int t2 = __builtin_amdgcn_update_dpp(0, v, 0x4E, 0xF, 0xF, true);   // quad_perm xor2
    x += __builtin_bit_cast(float, t2);
    v = __builtin_bit_cast(int, x);
    int t3 = __builtin_amdgcn_ds_swizzle(v, 0x101F);                    // xor4
    x += __builtin_bit_cast(float, t3);
    return x;
}

// ---------------- misc ----------------

__global__ void zerof_k(float* a, int n) {
    int i = blockIdx.x * blockDim.x + threadIdx.x;
    if (i < n) a[i] = 0.f;
}

__global__ void cvt_k(const float* __restrict__ x, ushort_t* __restrict__ o, int n) {
    int i = blockIdx.x * blockDim.x + threadIdx.x;
    int base = i * 4;
    if (base + 3 < n) {
        float4 v = *(const float4*)&x[base];
        uint2 pk;
        pk.x = cvtpk(v.x, v.y);
        pk.y = cvtpk(v.z, v.w);
        *(uint2*)&o[base] = pk;
    } else {
        for (int k = base; k < n; k++) o[k] = f2bf(x[k]);
    }
}

// ---------------- CSR build: block-local bucket sort (u32 packed pairs) ----------------
// pack = (dst&511)<<17 | src   (src < 2^17)

__global__ __launch_bounds__(256) void bin_k(const int* __restrict__ src,
                                             const int* __restrict__ dst,
                                             u32* __restrict__ binbuf,
                                             int* __restrict__ counts,     // [NBUK][NBLK]
                                             int* __restrict__ localoff) { // [NBUK][NBLK]
    __shared__ int hist[NBUK];
    __shared__ int excl[NBUK];
    __shared__ int cur[NBUK];
    __shared__ int tmp[256];
    __shared__ u32 pairs[EPB];
    int t = threadIdx.x;
    int blk = blockIdx.x;
    int e0 = blk * EPB;
    int totvalid = NE - e0; if (totvalid > EPB) totvalid = EPB;

    for (int i = t; i < NBUK; i += 256) hist[i] = 0;
    __syncthreads();

    int mysrc[8], mydst[8];
#pragma unroll
    for (int i = 0; i < 8; i++) {
        int e = e0 + i * 256 + t;
        bool v = e < NE;
        mysrc[i] = v ? src[e] : -1;
        mydst[i] = v ? dst[e] : -1;
        if (v) atomicAdd(&hist[mydst[i] >> 9], 1);
    }
    __syncthreads();

    int v = (t < NBUK) ? hist[t] : 0;
    tmp[t] = v;
    __syncthreads();
#pragma unroll
    for (int off = 1; off < 256; off <<= 1) {
        int a = (t >= off) ? tmp[t - off] : 0;
        __syncthreads();
        tmp[t] += a;
        __syncthreads();
    }
    if (t < NBUK) { excl[t] = tmp[t] - v; cur[t] = tmp[t] - v; }
    __syncthreads();

#pragma unroll
    for (int i = 0; i < 8; i++) {
        if (mydst[i] >= 0) {
            int b = mydst[i] >> 9;
            int p = atomicAdd(&cur[b], 1);
            pairs[p] = ((u32)(mydst[i] & 511) << 17) | (u32)mysrc[i];
        }
    }
    __syncthreads();

    for (int i = t; i < totvalid; i += 256) binbuf[(size_t)blk * EPB + i] = pairs[i];
    if (t < NBUK) {
        counts[t * NBLK + blk] = hist[t];
        localoff[t * NBLK + blk] = excl[t];
    }
}

__global__ __launch_bounds__(256) void scanA_k(const int* __restrict__ counts,
                                               int* __restrict__ chunkoff,
                                               int* __restrict__ buktot) {
    __shared__ int tmp[512];
    int b = blockIdx.x;
    int t = threadIdx.x;
    int v0 = (t < NBLK) ? counts[b * NBLK + t] : 0;
    int v1 = (256 + t < NBLK) ? counts[b * NBLK + 256 + t] : 0;
    tmp[t] = v0; tmp[t + 256] = v1;
    __syncthreads();
#pragma unroll
    for (int off = 1; off < 512; off <<= 1) {
        int a0 = (t >= off) ? tmp[t - off] : 0;
        int i1 = t + 256;
        int a1 = (i1 >= off) ? tmp[i1 - off] : 0;
        __syncthreads();
        tmp[t] += a0; tmp[i1] += a1;
        __syncthreads();
    }
    if (t < NBLK) chunkoff[b * NBLK + t] = tmp[t] - v0;
    if (256 + t < NBLK) chunkoff[b * NBLK + 256 + t] = tmp[t + 256] - v1;
    if (t == 0) buktot[b] = tmp[511];
}

__global__ __launch_bounds__(256) void scanB_k(const int* __restrict__ buktot,
                                               int* __restrict__ bukbase,
                                               int* __restrict__ rowstart) {
    __shared__ int tmp[256];
    int t = threadIdx.x;
    int v = (t < NBUK) ? buktot[t] : 0;
    tmp[t] = v;
    __syncthreads();
#pragma unroll
    for (int off = 1; off < 256; off <<= 1) {
        int a = (t >= off) ? tmp[t - off] : 0;
        __syncthreads();
        tmp[t] += a;
        __syncthreads();
    }
    if (t < NBUK) bukbase[t] = tmp[t] - v;
    if (t == 0) rowstart[NN] = NE;
}

__global__ __launch_bounds__(256) void csr_k(const u32* __restrict__ binbuf,
                                             const int* __restrict__ counts,
                                             const int* __restrict__ localoff,
                                             const int* __restrict__ chunkoff,
                                             const int* __restrict__ bukbase,
                                             int* __restrict__ rowstart,
                                             int* __restrict__ csr_src) {
    __shared__ u32 pairs[BCAP];
    __shared__ int csrb[BCAP];
    __shared__ int deg[512];
    __shared__ int excl[512];
    __shared__ int cur[512];
    __shared__ int tmp[512];
    int b = blockIdx.x;
    int t = threadIdx.x;
    int base = bukbase[b];
    int nbase = b << 9;
    int T = chunkoff[b * NBLK + NBLK - 1] + counts[b * NBLK + NBLK - 1];
    bool fits = (T <= BCAP);

    for (int i = t; i < 512; i += 256) deg[i] = 0;

    if (fits) {
        for (int blk = t; blk < NBLK; blk += 256) {
            int c = counts[b * NBLK + blk];
            int lo = localoff[b * NBLK + blk];
            int o = chunkoff[b * NBLK + blk];
            for (int i = 0; i < c; i++) pairs[o + i] = binbuf[(size_t)blk * EPB + lo + i];
        }
        __syncthreads();
        for (int i = t; i < T; i += 256) atomicAdd(&deg[pairs[i] >> 17], 1);
    } else {
        __syncthreads();
        for (int blk = 0; blk < NBLK; blk++) {
            int c = counts[b * NBLK + blk];
            int lo = localoff[b * NBLK + blk];
            for (int i = t; i < c; i += 256)
                atomicAdd(&deg[binbuf[(size_t)blk * EPB + lo + i] >> 17], 1);
        }
    }
    __syncthreads();

    int v0 = deg[t], v1 = deg[t + 256];
    tmp[t] = v0; tmp[t + 256] = v1;
    __syncthreads();
#pragma unroll
    for (int off = 1; off < 512; off <<= 1) {
        int a0 = (t >= off) ? tmp[t - off] : 0;
        int i1 = t + 256;
        int a1 = (i1 >= off) ? tmp[i1 - off] : 0;
        __syncthreads();
        tmp[t] += a0; tmp[i1] += a1;
        __syncthreads();
    }
    excl[t] = tmp[t] - v0; excl[t + 256] = tmp[t + 256] - v1;
    cur[t] = excl[t]; cur[t + 256] = excl[t + 256];
    __syncthreads();

    for (int i = t; i < 512; i += 256) {
        int n = nbase + i;
        if (n < NN) rowstart[n] = base + excl[i];
    }

    if (fits) {
        for (int i = t; i < T; i += 256) {
            u32 p = pairs[i];
            int pos = atomicAdd(&cur[p >> 17], 1);
            csrb[pos] = (int)(p & 0x1FFFFu);
        }
        __syncthreads();
        for (int i = t; i < T; i += 256) csr_src[base + i] = csrb[i];
    } else {
        for (int blk = 0; blk < NBLK; blk++) {
            int c = counts[b * NBLK + blk];
            int lo = localoff[b * NBLK + blk];
            for (int i = t; i < c; i += 256) {
                u32 p = binbuf[(size_t)blk * EPB + lo + i];
                int pos = atomicAdd(&cur[p >> 17], 1);
                csr_src[base + pos] = (int)(p & 0x1FFFFu);
            }
        }
    }
}

// ---------------- W pre-pack (doubles as swapped-A fragments) ----------------

__global__ __launch_bounds__(64) void packw_k(const float* __restrict__ Wq,
                                              const float* __restrict__ Wk,
                                              const float* __restrict__ Wv,
                                              const float* __restrict__ Ws_,
                                              ushort_t* __restrict__ wpack) {
    int mat = blockIdx.x & 3, layer = blockIdx.x >> 2;
    const float* W = ((mat == 0) ? Wq : (mat == 1) ? Wk : (mat == 2) ? Wv : Ws_) + layer * DD * DD;
    int lane = threadIdx.x;
    int lq = lane >> 4, ln = lane & 15;
#pragma unroll
    for (int ct = 0; ct < 4; ct++) {
#pragma unroll
        for (int ks = 0; ks < 2; ks++) {
#pragma unroll
            for (int j = 0; j < 8; j++) {
                float v = W[(ks * 32 + lq * 8 + j) * DD + ct * 16 + ln];
                wpack[((size_t)(blockIdx.x * 8 + ct * 2 + ks)) * 512 + lane * 8 + j] = f2bf(v);
            }
        }
    }
}

// ---------------- fused 4-matrix MFMA GEMM, swapped operands ----------------
// D = W^T @ h^T: lane(ln,lq) holds out[node=rt*16+ln][cols ct*16+lq*4 .. +3]
// -> 2 cvt_pk + one 8B store per tile. No LDS, no barriers.

__global__ __launch_bounds__(256) void gemm4_k(const ushort_t* __restrict__ hbf,
                                               const ushort_t* __restrict__ wpl,
                                               const float* __restrict__ bq_, const float* __restrict__ bk_,
                                               const float* __restrict__ bv_, const float* __restrict__ bs_,
                                               ushort_t* __restrict__ qo, ushort_t* __restrict__ ko,
                                               ushort_t* __restrict__ vo, ushort_t* __restrict__ so) {
    int t = threadIdx.x;
    int lane = t & 63, wv = t >> 6;
    int ln = lane & 15, lq = lane >> 4;
    int rowbase = blockIdx.x * 64;

    const float* bsel = (wv == 0) ? bq_ : (wv == 1) ? bk_ : (wv == 2) ? bv_ : bs_;
    ushort_t* osel    = (wv == 0) ? qo : (wv == 1) ? ko : (wv == 2) ? vo : so;

    short8v wfrag[4][2];
#pragma unroll
    for (int ct = 0; ct < 4; ct++)
#pragma unroll
        for (int ks = 0; ks < 2; ks++)
            wfrag[ct][ks] = *(const short8v*)&wpl[((size_t)(wv * 8 + ct * 2 + ks)) * 512 + lane * 8];

    float4 bias[4];
#pragma unroll
    for (int ct = 0; ct < 4; ct++) bias[ct] = *(const float4*)&bsel[ct * 16 + lq * 4];

#pragma unroll
    for (int rt = 0; rt < 4; rt++) {
        int grow = rowbase + rt * 16 + ln;
        bool rv = grow < NN;
        int gr = rv ? grow : NN - 1;
        short8v h0 = *(const short8v*)&hbf[(size_t)gr * DD + lq * 8];
        short8v h1 = *(const short8v*)&hbf[(size_t)gr * DD + 32 + lq * 8];
#pragma unroll
        for (int ct = 0; ct < 4; ct++) {
            f32x4 acc;
            acc[0] = bias[ct].x; acc[1] = bias[ct].y; acc[2] = bias[ct].z; acc[3] = bias[ct].w;
            acc = __builtin_amdgcn_mfma_f32_16x16x32_bf16(wfrag[ct][0], h0, acc, 0, 0, 0);
            acc = __builtin_amdgcn_mfma_f32_16x16x32_bf16(wfrag[ct][1], h1, acc, 0, 0, 0);
            if (rv) {
                uint2 pk;
                pk.x = cvtpk(acc[0], acc[1]);
                pk.y = cvtpk(acc[2], acc[3]);
                *(uint2*)&osel[(size_t)grow * DD + ct * 16 + lq * 4] = pk;
            }
        }
    }
}

// ---------------- single-pass online-softmax aggregate + skip + relu ----------------
// 4 nodes/wave; node = lane>>4 pair of 8-lane groups; lane&7 holds dims 8j..8j+7.
// log2-domain deferred-max softmax; DPP group reduce; 2-deep csr prefetch.

#define SCLOG2E 0.18033688011112042f  // 0.125 * log2(e)

__global__ __launch_bounds__(256) void agg_k(const ushort_t* __restrict__ qb,
                                             const ushort_t* __restrict__ kb,
                                             const ushort_t* __restrict__ vb,
                                             const ushort_t* __restrict__ skb,
                                             const int* __restrict__ rowstart,
                                             const int* __restrict__ csr_src,
                                             ushort_t* __restrict__ hout) {
    int wv = threadIdx.x >> 6, lane = threadIdx.x & 63;
    int g = lane >> 3, j = lane & 7, sub = g & 1;
    int nid = blockIdx.x * 16 + wv * 4 + (g >> 1);
    bool nv = nid < NN;
    int nc = nv ? nid : NN - 1;
    int r0 = rowstart[nc];
    int r1 = nv ? rowstart[nc + 1] : r0;

    short8v q8 = *(const short8v*)&qb[(size_t)nc * DD + 8 * j];
    float q0 = bf2f((ushort_t)q8[0]), q1 = bf2f((ushort_t)q8[1]);
    float q2 = bf2f((ushort_t)q8[2]), q3 = bf2f((ushort_t)q8[3]);
    float q4 = bf2f((ushort_t)q8[4]), q5 = bf2f((ushort_t)q8[5]);
    float q6 = bf2f((ushort_t)q8[6]), q7 = bf2f((ushort_t)q8[7]);

    float m = -1.0e38f, se = 0.f;
    float a0 = 0.f, a1 = 0.f, a2 = 0.f, a3 = 0.f, a4 = 0.f, a5 = 0.f, a6 = 0.f, a7 = 0.f;

    int clampE = r1 - 1; if (clampE < 0) clampE = 0;
    int e = r0 + sub;
    int eN = e + 2;
    int sC = csr_src[e < clampE ? e : clampE];
    int sN = csr_src[eN < clampE ? eN : clampE];
    short8v kC = *(const short8v*)&kb[(size_t)sC * DD + 8 * j];
    short8v vC = *(const short8v*)&vb[(size_t)sC * DD + 8 * j];

    for (;;) {
        bool act = e < r1;
        if (!__ballot(act)) break;
        int eNN = eN + 2;
        int sNN = csr_src[eNN < clampE ? eNN : clampE];
        short8v kN = *(const short8v*)&kb[(size_t)sN * DD + 8 * j];
        short8v vN = *(const short8v*)&vb[(size_t)sN * DD + 8 * j];

        float dp = q0 * bf2f((ushort_t)kC[0]) + q1 * bf2f((ushort_t)kC[1])
                 + q2 * bf2f((ushort_t)kC[2]) + q3 * bf2f((ushort_t)kC[3])
                 + q4 * bf2f((ushort_t)kC[4]) + q5 * bf2f((ushort_t)kC[5])
                 + q6 * bf2f((ushort_t)kC[6]) + q7 * bf2f((ushort_t)kC[7]);
        dp = sum8(dp);

        float w = 0.f;
        if (act) {
            float sc = dp * SCLOG2E;
            if (sc <= m + 11.5f) {
                w = exp2f(sc - m);
            } else {  // rare: first edge or max jumped
                float cc = exp2f(m - sc);
                se *= cc; a0 *= cc; a1 *= cc; a2 *= cc; a3 *= cc;
                a4 *= cc; a5 *= cc; a6 *= cc; a7 *= cc;
                m = sc; w = 1.f;
            }
        }
        se += w;
        a0 += w * bf2f((ushort_t)vC[0]); a1 += w * bf2f((ushort_t)vC[1]);
        a2 += w * bf2f((ushort_t)vC[2]); a3 += w * bf2f((ushort_t)vC[3]);
        a4 += w * bf2f((ushort_t)vC[4]); a5 += w * bf2f((ushort_t)vC[5]);
        a6 += w * bf2f((ushort_t)vC[6]); a7 += w * bf2f((ushort_t)vC[7]);

        e = eN; eN = eNN; sC = sN; sN = sNN; kC = kN; vC = vN;
    }

    // combine the node's two groups (xor8)
    float M = fmaxf(m, __shfl_xor(m, 8));
    float cc = exp2f(m - M);
    se *= cc; a0 *= cc; a1 *= cc; a2 *= cc; a3 *= cc;
    a4 *= cc; a5 *= cc; a6 *= cc; a7 *= cc;
    se += __shfl_xor(se, 8);
    a0 += __shfl_xor(a0, 8); a1 += __shfl_xor(a1, 8);
    a2 += __shfl_xor(a2, 8); a3 += __shfl_xor(a3, 8);
    a4 += __shfl_xor(a4, 8); a5 += __shfl_xor(a5, 8);
    a6 += __shfl_xor(a6, 8); a7 += __shfl_xor(a7, 8);

    if (sub == 0 && nv) {
        float inv = 1.0f / (se + 1e-16f);
        short8v sk8 = *(const short8v*)&skb[(size_t)nc * DD + 8 * j];
        float o0 = fmaxf(a0 * inv + bf2f((ushort_t)sk8[0]), 0.f);
        float o1 = fmaxf(a1 * inv + bf2f((ushort_t)sk8[1]), 0.f);
        float o2 = fmaxf(a2 * inv + bf2f((ushort_t)sk8[2]), 0.f);
        float o3 = fmaxf(a3 * inv + bf2f((ushort_t)sk8[3]), 0.f);
        float o4 = fmaxf(a4 * inv + bf2f((ushort_t)sk8[4]), 0.f);
        float o5 = fmaxf(a5 * inv + bf2f((ushort_t)sk8[5]), 0.f);
        float o6 = fmaxf(a6 * inv + bf2f((ushort_t)sk8[6]), 0.f);
        float o7 = fmaxf(a7 * inv + bf2f((ushort_t)sk8[7]), 0.f);
        u32x4 pk;
        pk[0] = cvtpk(o0, o1); pk[1] = cvtpk(o2, o3);
        pk[2] = cvtpk(o4, o5); pk[3] = cvtpk(o6, o7);
        *(u32x4*)&hout[(size_t)nid * DD + 8 * j] = pk;
    }
}

// ---------------- global add pool ----------------

#define POOL_ROWS 128

__global__ __launch_bounds__(256) void pool_k(const ushort_t* __restrict__ h,
                                              const int* __restrict__ batch,
                                              float* __restrict__ pooled) {
    int i0 = blockIdx.x * POOL_ROWS;
    int i1 = i0 + POOL_ROWS; if (i1 > NN) i1 = NN;
    int lane = threadIdx.x & 63;
    int wv = threadIdx.x >> 6;
    float acc = 0.f;
    int gcur = -1;
    for (int i = i0 + wv; i < i1; i += 4) {
        int gi = batch[i];
        if (gi != gcur) {
            if (gcur >= 0) atomicAdd(&pooled[gcur * DD + lane], acc);
            gcur = gi; acc = 0.f;
        }
        acc += bf2f(h[(size_t)i * DD + lane]);
    }
    if (gcur >= 0) atomicAdd(&pooled[gcur * DD + lane], acc);
}

// ---------------- head ----------------

__global__ __launch_bounds__(64) void head_k(const float* __restrict__ pooled2,
                                             const float* __restrict__ W1,
                                             const float* __restrict__ b1,
                                             const float* __restrict__ W2,
                                             const float* __restrict__ b2,
                                             float* __restrict__ out) {
    int g = blockIdx.x;
    int c = threadIdx.x;
    __shared__ float pg[64], p[64];
    pg[c] = pooled2[g * DD + c];
    __syncthreads();
    float a = b1[c];
#pragma unroll 8
    for (int kk = 0; kk < 64; kk++) a += pg[kk] * W1[kk * DD + c];
    p[c] = fmaxf(a, 0.f);
    __syncthreads();
    if (c < 10) {
        float o = b2[c];
#pragma unroll 8
        for (int kk = 0; kk < 64; kk++) o += p[kk] * W2[kk * 10 + c];
        out[g * 10 + c] = o;
    }
}

// ---------------- launch ----------------

extern "C" void kernel_launch(void* const* d_in, const int* in_sizes, int n_in,
                              void* d_out, int out_size, void* d_ws, size_t ws_size,
                              hipStream_t stream) {
    const float* x    = (const float*)d_in[0];
    const int*   ei   = (const int*)d_in[1];
    const int*   batch= (const int*)d_in[2];
    const float* Wq   = (const float*)d_in[3];
    const float* bq   = (const float*)d_in[4];
    const float* Wk   = (const float*)d_in[5];
    const float* bk   = (const float*)d_in[6];
    const float* Wv   = (const float*)d_in[7];
    const float* bv   = (const float*)d_in[8];
    const float* Wsp  = (const float*)d_in[9];
    const float* bsp  = (const float*)d_in[10];
    const float* W1   = (const float*)d_in[11];
    const float* b1   = (const float*)d_in[12];
    const float* W2   = (const float*)d_in[13];
    const float* b2   = (const float*)d_in[14];
    float* out = (float*)d_out;
    float* pooled = out + NG * 10;

    const int* srcv = ei;
    const int* dstv = ei + NE;

    const size_t NEL = (size_t)NN * DD;
    ushort_t* hbf = (ushort_t*)d_ws;                 // [NN][64]
    ushort_t* qb  = hbf + NEL;
    ushort_t* kb  = qb  + NEL;
    ushort_t* vb  = kb  + NEL;
    ushort_t* skb = vb  + NEL;
    u32* binbuf   = (u32*)(skb + NEL);               // [NBLK*EPB]
    int* counts   = (int*)(binbuf + (size_t)NBLK * EPB);
    int* localoff = counts + NBUK * NBLK;
    int* chunkoff = localoff + NBUK * NBLK;
    int* buktot   = chunkoff + NBUK * NBLK;
    int* bukbase  = buktot + NBUK;
    int* rowstart = bukbase + NBUK;                  // [NN+1]
    int* csr_src  = rowstart + (NN + 1);             // [NE]
    ushort_t* wpack = (ushort_t*)(csr_src + NE);     // 12*4096 bf16

    int totOut = NG * 10 + NL * NG * DD;

    zerof_k<<<(totOut + 255) / 256, 256, 0, stream>>>(out, totOut);
    cvt_k<<<((int)NEL / 4 + 255) / 256, 256, 0, stream>>>(x, hbf, (int)NEL);
    packw_k<<<NL * 4, 64, 0, stream>>>(Wq, Wk, Wv, Wsp, wpack);

    bin_k<<<NBLK, 256, 0, stream>>>(srcv, dstv, binbuf, counts, localoff);
    scanA_k<<<NBUK, 256, 0, stream>>>(counts, chunkoff, buktot);
    scanB_k<<<1, 256, 0, stream>>>(buktot, bukbase, rowstart);
    csr_k<<<NBUK, 256, 0, stream>>>(binbuf, counts, localoff, chunkoff, bukbase,
                                    rowstart, csr_src);

    int gtiles = (NN + 63) / 64;
    int poolblocks = (NN + POOL_ROWS - 1) / POOL_ROWS;
    for (int l = 0; l < NL; l++) {
        gemm4_k<<<gtiles, 256, 0, stream>>>(hbf, wpack + (size_t)l * 4 * 8 * 512,
                                            bq + l * DD, bk + l * DD, bv + l * DD, bsp + l * DD,
                                            qb, kb, vb, skb);
        agg_k<<<(NN + 15) / 16, 256, 0, stream>>>(qb, kb, vb, skb, rowstart, csr_src, hbf);
        pool_k<<<poolblocks, 256, 0, stream>>>(hbf, batch, pooled + l * NG * DD);
    }
    head_k<<<NG, 64, 0, stream>>>(pooled + 2 * NG * DD, W1, b1, W2, b2, out);
}